// Round 1
// 785.811 us; speedup vs baseline: 1.0363x; 1.0363x over previous
//
#include <hip/hip_runtime.h>

#define Tn      8192
#define Cn      1024
#define En      8
#define Fn      2752
#define MAXROWS 18432
#define NT1     16      // Cn/64 K-tiles for gemm1
#define NT2     43      // Fn/64 K-tiles for gemm2

typedef __bf16 bf16;
typedef bf16  bf16x8 __attribute__((ext_vector_type(8)));
typedef bf16  bf16x4 __attribute__((ext_vector_type(4)));
typedef float f32x4  __attribute__((ext_vector_type(4)));

__device__ __forceinline__ void gload16(const bf16* g, bf16* l) {
  __builtin_amdgcn_global_load_lds(
      (const __attribute__((address_space(1))) unsigned int*)g,
      (__attribute__((address_space(3))) unsigned int*)l, 16, 0, 0);
}

#define BARRIER() __builtin_amdgcn_s_barrier()
#define LGKM0()   asm volatile("s_waitcnt lgkmcnt(0)" ::: "memory")
#define VMCNT(N)  asm volatile("s_waitcnt vmcnt(" #N ")" ::: "memory")
#define MFMA(d, va, vb) d = __builtin_amdgcn_mfma_f32_16x16x32_bf16(va, vb, d, 0, 0, 0)

// ---------------- gating ------------------------------------------------------
__global__ __launch_bounds__(256) void gate_kernel(
    const float* __restrict__ x, const float* __restrict__ wgate,
    int* __restrict__ topk_i, float* __restrict__ topk_w, int* __restrict__ counts)
{
  int lane = threadIdx.x & 63;
  int wid  = threadIdx.x >> 6;
  int t = blockIdx.x * 4 + wid;
  const float* xr = x + (size_t)t * Cn;
  float acc[En];
#pragma unroll
  for (int e = 0; e < En; ++e) acc[e] = 0.f;
  for (int c = lane; c < Cn; c += 64) {
    float xv = xr[c];
#pragma unroll
    for (int e = 0; e < En; ++e) acc[e] = fmaf(xv, wgate[e * Cn + c], acc[e]);
  }
#pragma unroll
  for (int e = 0; e < En; ++e) {
#pragma unroll
    for (int o = 32; o > 0; o >>= 1) acc[e] += __shfl_xor(acc[e], o, 64);
  }
  if (lane == 0) {
    float mx = acc[0];
#pragma unroll
    for (int e = 1; e < En; ++e) mx = fmaxf(mx, acc[e]);
    float p[En], Z = 0.f;
#pragma unroll
    for (int e = 0; e < En; ++e) { p[e] = __expf(acc[e] - mx); Z += p[e]; }
    int i0 = 0;
#pragma unroll
    for (int e = 1; e < En; ++e) if (p[e] > p[i0]) i0 = e;
    int i1 = (i0 == 0) ? 1 : 0;
#pragma unroll
    for (int e = 0; e < En; ++e) if (e != i0 && p[e] > p[i1]) i1 = e;
    float s0 = p[i0] / Z, s1 = p[i1] / Z;
    float inv = 1.f / (s0 + s1 + 1e-9f);
    topk_i[2 * t] = i0;       topk_i[2 * t + 1] = i1;
    topk_w[2 * t] = s0 * inv; topk_w[2 * t + 1] = s1 * inv;
    atomicAdd(&counts[i0], 1);
    atomicAdd(&counts[i1], 1);
  }
}

__global__ void offsets_kernel(const int* __restrict__ counts,
                               int* __restrict__ fill, int* __restrict__ off)
{
  if (threadIdx.x == 0 && blockIdx.x == 0) {
    int o = 0;
    for (int e = 0; e < En; ++e) {
      off[e]  = o;
      fill[e] = o;
      o += (counts[e] + 255) & ~255;   // 256-row expert padding (BM=256)
    }
    off[En] = o;
  }
}

__global__ __launch_bounds__(256) void scatter_kernel(
    const int* __restrict__ topk_i, const float* __restrict__ topk_w,
    int* __restrict__ fill, int* __restrict__ tok_list, float* __restrict__ wgt_list,
    int* __restrict__ inv_rows)
{
  int t = blockIdx.x * 256 + threadIdx.x;
#pragma unroll
  for (int j = 0; j < 2; ++j) {
    int e = topk_i[2 * t + j];
    int pos = atomicAdd(&fill[e], 1);
    tok_list[pos] = t;
    wgt_list[pos] = topk_w[2 * t + j];
    inv_rows[2 * t + j] = pos;
  }
}

__global__ __launch_bounds__(256) void gather_x(
    const float* __restrict__ x, const int* __restrict__ tok_list, bf16* __restrict__ xg)
{
  int row = blockIdx.x;
  int tok = tok_list[row];
  int c = threadIdx.x * 4;
  float4 v = make_float4(0.f, 0.f, 0.f, 0.f);
  if (tok >= 0) v = *(const float4*)(x + (size_t)tok * Cn + c);
  bf16x4 pv;
  pv[0] = (bf16)v.x; pv[1] = (bf16)v.y; pv[2] = (bf16)v.z; pv[3] = (bf16)v.w;
  *(bf16x4*)(xg + (size_t)row * Cn + c) = pv;
}

// ---------------- fast transpose + fp32->bf16 ---------------------------------
__global__ __launch_bounds__(256) void transpose_cvt(
    const float* __restrict__ src, bf16* __restrict__ dst, int M, int N)
{
  __shared__ float L[64][65];
  src += (size_t)blockIdx.z * M * N;
  dst += (size_t)blockIdx.z * M * N;
  const int bm = blockIdx.x * 64;
  const int bn = blockIdx.y * 64;
  const int tid = threadIdx.x;
  const int mr = tid >> 4, nseg = tid & 15;
#pragma unroll
  for (int p = 0; p < 4; ++p) {
    int m = p * 16 + mr;
    float4 v = *(const float4*)(src + (size_t)(bm + m) * N + bn + nseg * 4);
    L[nseg * 4 + 0][m] = v.x;
    L[nseg * 4 + 1][m] = v.y;
    L[nseg * 4 + 2][m] = v.z;
    L[nseg * 4 + 3][m] = v.w;
  }
  __syncthreads();
  const int nr = tid >> 3, mseg = tid & 7;
#pragma unroll
  for (int q = 0; q < 2; ++q) {
    int n = q * 32 + nr;
    bf16x8 w;
#pragma unroll
    for (int j = 0; j < 8; ++j) w[j] = (bf16)L[n][mseg * 8 + j];
    *(bf16x8*)(dst + (size_t)(bn + n) * M + bm + mseg * 8) = w;
  }
}

// LDS K-tile layout (BK=64 stored as 2 x 32-element ksub; 64B rows = 4 x 16B slots):
//   LDS[s][row][slot] = G[row][slot ^ ((row>>1)&3)]  within ksub s
// staging lane: row = tid>>2, gseg = (tid&3) ^ ((tid>>3)&3)  (conflict-free, proven)
// frag read:   slot = q ^ ((fr>>1)&3),  q = lane>>4, fr = lane&15

// ---------------- GEMM1: h = wgt * silu(xg@wgT') * (xg@wuT') ------------------
// 256 x (128 gate + 128 up), BK=64, 8 waves, 128KB dbuf LDS, 4-phase counted-vmcnt.
// grid: x = n (22, fast), y = m (rows/256).
__global__ __launch_bounds__(512, 2) void gemm1_kernel(
    const bf16* __restrict__ xg, const bf16* __restrict__ wgT, const bf16* __restrict__ wuT,
    const int* __restrict__ off, const int* __restrict__ counts,
    const float* __restrict__ wgt_list, bf16* __restrict__ h, int row_lo)
{
  const int m0 = row_lo + blockIdx.y * 256;
  if (m0 >= off[En]) return;
  int e = 0;
  while (off[e + 1] <= m0) ++e;
  const int base = off[e], cnt = counts[e];
  const int n0 = blockIdx.x * 128;

  // buffer layout (elements): A [2s][256r][32] @0 (16384) ; Bg [2s][128r][32] @16384 ; Bu @24576
  __shared__ bf16 sm[2][32768];   // 128 KB

  const int tid = threadIdx.x;
  const int lane = tid & 63, wid = tid >> 6;
  const int wm  = (wid >> 2) * 128;       // wave m-half: 0 / 128
  const int wnv = (wid & 3) * 32;         // wave n-quarter within 128
  const int fr = lane & 15, q = lane >> 4;
  const int lrow = tid >> 2;              // staging row 0..127
  const int gseg = (tid & 3) ^ ((tid >> 3) & 3);
  const int tt = (q ^ ((fr >> 1) & 3)) * 8;

  const bf16* wge = wgT + (size_t)e * ((size_t)Fn * Cn);
  const bf16* wue = wuT + (size_t)e * ((size_t)Fn * Cn);
  int brow = n0 + lrow; if (brow > Fn - 1) brow = Fn - 1;   // ragged N tail clamp
  const bf16* ag0 = xg  + (size_t)(m0 + lrow) * Cn + gseg * 8;
  const bf16* ag1 = ag0 + (size_t)128 * Cn;
  const bf16* bgp = wge + (size_t)brow * Cn + gseg * 8;
  const bf16* bup = wue + (size_t)brow * Cn + gseg * 8;

  f32x4 accg[2][4][2], accu[2][4][2];
#pragma unroll
  for (int mh = 0; mh < 2; ++mh)
#pragma unroll
    for (int mi = 0; mi < 4; ++mi)
#pragma unroll
      for (int ni = 0; ni < 2; ++ni) {
        accg[mh][mi][ni] = (f32x4)(0.f);
        accu[mh][mi][ni] = (f32x4)(0.f);
      }

  bf16x8 a[4][2], bg[2][2], bu[2][2];

#define STG1(SRC, KOFF, DOFF) gload16((SRC) + (KOFF), Nx + (DOFF) + tid * 8)

  // prologue: stage tile 0 into buf 0, issue order = use order
  {
    bf16* Nx = &sm[0][0];
    STG1(ag0, 0, 0);     STG1(ag0, 32, 8192);    // Ah0 (needed P0)
    STG1(ag1, 0, 4096);  STG1(ag1, 32, 12288);   // Ah1 (needed P0)
    STG1(bgp, 0, 16384); STG1(bgp, 32, 20480);   // Bg  (needed P0)
    STG1(bup, 0, 24576); STG1(bup, 32, 28672);   // Bu  (needed P1)
  }
  VMCNT(2);              // Ah0,Ah1,Bg complete; Bu may be in flight
  BARRIER();

  for (int kt = 0; kt < NT1; ++kt) {
    const int b = kt & 1;
    const bf16* S = &sm[b][0];
    bf16* Nx = &sm[b ^ 1][0];
    const bool lastt = (kt == NT1 - 1);
    const int ko = (kt + 1) * 64;

    // ---- P0: read a-low + bg ; stage Ah0' ; MFMA gate m-low
#pragma unroll
    for (int mi = 0; mi < 4; ++mi)
#pragma unroll
      for (int s = 0; s < 2; ++s)
        a[mi][s] = *(const bf16x8*)(S + s * 8192 + (wm + mi * 16 + fr) * 32 + tt);
#pragma unroll
    for (int ni = 0; ni < 2; ++ni)
#pragma unroll
      for (int s = 0; s < 2; ++s)
        bg[ni][s] = *(const bf16x8*)(S + 16384 + s * 4096 + (wnv + ni * 16 + fr) * 32 + tt);
    if (!lastt) { STG1(ag0, ko, 0); STG1(ag0, ko + 32, 8192); }
    BARRIER();
    LGKM0();
    __builtin_amdgcn_s_setprio(1);
#pragma unroll
    for (int s = 0; s < 2; ++s)
#pragma unroll
      for (int mi = 0; mi < 4; ++mi)
#pragma unroll
        for (int ni = 0; ni < 2; ++ni)
          MFMA(accg[0][mi][ni], a[mi][s], bg[ni][s]);
    __builtin_amdgcn_s_setprio(0);
    if (lastt) { VMCNT(0); } else { VMCNT(2); }   // Bu(kt) ready for P1
    BARRIER();

    // ---- P1: read bu ; stage Ah1' ; MFMA up m-low
#pragma unroll
    for (int ni = 0; ni < 2; ++ni)
#pragma unroll
      for (int s = 0; s < 2; ++s)
        bu[ni][s] = *(const bf16x8*)(S + 24576 + s * 4096 + (wnv + ni * 16 + fr) * 32 + tt);
    if (!lastt) { STG1(ag1, ko, 4096); STG1(ag1, ko + 32, 12288); }
    BARRIER();
    LGKM0();
    __builtin_amdgcn_s_setprio(1);
#pragma unroll
    for (int s = 0; s < 2; ++s)
#pragma unroll
      for (int mi = 0; mi < 4; ++mi)
#pragma unroll
        for (int ni = 0; ni < 2; ++ni)
          MFMA(accu[0][mi][ni], a[mi][s], bu[ni][s]);
    __builtin_amdgcn_s_setprio(0);
    BARRIER();

    // ---- P2: read a-high ; stage Bg' ; MFMA gate m-high
#pragma unroll
    for (int mi = 0; mi < 4; ++mi)
#pragma unroll
      for (int s = 0; s < 2; ++s)
        a[mi][s] = *(const bf16x8*)(S + s * 8192 + (wm + 64 + mi * 16 + fr) * 32 + tt);
    if (!lastt) { STG1(bgp, ko, 16384); STG1(bgp, ko + 32, 20480); }
    BARRIER();
    LGKM0();
    __builtin_amdgcn_s_setprio(1);
#pragma unroll
    for (int s = 0; s < 2; ++s)
#pragma unroll
      for (int mi = 0; mi < 4; ++mi)
#pragma unroll
        for (int ni = 0; ni < 2; ++ni)
          MFMA(accg[1][mi][ni], a[mi][s], bg[ni][s]);
    __builtin_amdgcn_s_setprio(0);
    BARRIER();

    // ---- P3: stage Bu' ; MFMA up m-high ; boundary counted wait
    if (!lastt) { STG1(bup, ko, 24576); STG1(bup, ko + 32, 28672); }
    BARRIER();
    __builtin_amdgcn_s_setprio(1);
#pragma unroll
    for (int s = 0; s < 2; ++s)
#pragma unroll
      for (int mi = 0; mi < 4; ++mi)
#pragma unroll
        for (int ni = 0; ni < 2; ++ni)
          MFMA(accu[1][mi][ni], a[mi][s], bu[ni][s]);
    __builtin_amdgcn_s_setprio(0);
    if (!lastt) { VMCNT(2); }   // Ah0',Ah1',Bg' ready for next P0; Bu' stays in flight
    BARRIER();
  }
#undef STG1

  // epilogue: h = wgt * u * silu(g)
  const int rq = (lane >> 4) * 4, cl = lane & 15;
#pragma unroll
  for (int mh = 0; mh < 2; ++mh)
#pragma unroll
    for (int mi = 0; mi < 4; ++mi)
#pragma unroll
      for (int r = 0; r < 4; ++r) {
        int grow = m0 + wm + mh * 64 + mi * 16 + rq + r;
        float w = (grow - base < cnt) ? wgt_list[grow] : 0.f;
        bf16* hr = h + (size_t)(grow - row_lo) * Fn + n0;
#pragma unroll
        for (int ni = 0; ni < 2; ++ni) {
          int fc = wnv + ni * 16;
          if (n0 + fc < Fn) {
            float g = accg[mh][mi][ni][r], u = accu[mh][mi][ni][r];
            hr[fc + cl] = (bf16)(w * u * (g / (1.f + __expf(-g))));
          }
        }
      }
}

// ---------------- GEMM2: h2[row] = h[row] @ wdT' ------------------------------
// 128 x 256 (two 128-col halves), BK=64, 8 waves, 96KB dbuf LDS, 2-phase counted-vmcnt.
// grid: x = n (4, fast), y = m (rows/128).
__global__ __launch_bounds__(512, 2) void gemm2_kernel(
    const bf16* __restrict__ h, const bf16* __restrict__ wdT,
    const int* __restrict__ off, bf16* __restrict__ h2, int row_lo)
{
  const int m0 = row_lo + blockIdx.y * 128;
  if (m0 >= off[En]) return;
  int e = 0;
  while (off[e + 1] <= m0) ++e;
  const int n0 = blockIdx.x * 256;

  // buffer layout (elements): A [2s][128r][32] @0 (8192) ; B [2s][256r][32] @8192 (16384)
  __shared__ bf16 sm[2][24576];   // 96 KB

  const int tid = threadIdx.x;
  const int lane = tid & 63, wid = tid >> 6;
  const int wm  = (wid >> 2) * 64;        // wave m-half: 0 / 64
  const int wnv = (wid & 3) * 32;         // wave n-quarter within each 128-half
  const int fr = lane & 15, q = lane >> 4;
  const int lrow = tid >> 2;
  const int gseg = (tid & 3) ^ ((tid >> 3) & 3);
  const int tt = (q ^ ((fr >> 1) & 3)) * 8;

  const bf16* wde = wdT + (size_t)e * ((size_t)Cn * Fn);
  const bf16* agp = h   + (size_t)(m0 - row_lo + lrow) * Fn + gseg * 8;
  const bf16* b0p = wde + (size_t)(n0 + lrow) * Fn + gseg * 8;
  const bf16* b1p = b0p + (size_t)128 * Fn;

  f32x4 accg[4][2], accu[4][2];
#pragma unroll
  for (int mi = 0; mi < 4; ++mi)
#pragma unroll
    for (int ni = 0; ni < 2; ++ni) { accg[mi][ni] = (f32x4)(0.f); accu[mi][ni] = (f32x4)(0.f); }

  bf16x8 a[4][2], bg[2][2], bu[2][2];

#define STG2(SRC, KOFF, DOFF) gload16((SRC) + (KOFF), Nx + (DOFF) + tid * 8)

  // prologue: stage tile 0 into buf 0 (use order: A, Bh0, Bh1)
  {
    bf16* Nx = &sm[0][0];
    STG2(agp, 0, 0);     STG2(agp, 32, 4096);     // A s0, s1
    STG2(b0p, 0, 8192);  STG2(b0p, 32, 16384);    // Bh0 s0, s1
    STG2(b1p, 0, 12288); STG2(b1p, 32, 20480);    // Bh1 s0, s1
  }
  VMCNT(2);              // A + Bh0 complete; Bh1 may be in flight
  BARRIER();

  for (int kt = 0; kt < NT2; ++kt) {
    const int b = kt & 1;
    const bf16* S = &sm[b][0];
    bf16* Nx = &sm[b ^ 1][0];
    const bool lastt = (kt == NT2 - 1);
    const int ko = (kt + 1) * 64;

    // ---- P0: read a + b-lowhalf ; stage {As0', As1', B0s0'} ; MFMA low-half cols
#pragma unroll
    for (int mi = 0; mi < 4; ++mi)
#pragma unroll
      for (int s = 0; s < 2; ++s)
        a[mi][s] = *(const bf16x8*)(S + s * 4096 + (wm + mi * 16 + fr) * 32 + tt);
#pragma unroll
    for (int ni = 0; ni < 2; ++ni)
#pragma unroll
      for (int s = 0; s < 2; ++s)
        bg[ni][s] = *(const bf16x8*)(S + 8192 + s * 8192 + (wnv + ni * 16 + fr) * 32 + tt);
    if (!lastt) { STG2(agp, ko, 0); STG2(agp, ko + 32, 4096); STG2(b0p, ko, 8192); }
    BARRIER();
    LGKM0();
    __builtin_amdgcn_s_setprio(1);
#pragma unroll
    for (int s = 0; s < 2; ++s)
#pragma unroll
      for (int mi = 0; mi < 4; ++mi)
#pragma unroll
        for (int ni = 0; ni < 2; ++ni)
          MFMA(accg[mi][ni], a[mi][s], bg[ni][s]);
    __builtin_amdgcn_s_setprio(0);
    if (lastt) { VMCNT(0); } else { VMCNT(3); }   // Bh1(kt) ready for P1
    BARRIER();

    // ---- P1: read b-highhalf ; stage {B0s1', B1s0', B1s1'} ; MFMA high-half cols
#pragma unroll
    for (int ni = 0; ni < 2; ++ni)
#pragma unroll
      for (int s = 0; s < 2; ++s)
        bu[ni][s] = *(const bf16x8*)(S + 8192 + s * 8192 + (128 + wnv + ni * 16 + fr) * 32 + tt);
    if (!lastt) { STG2(b0p, ko + 32, 16384); STG2(b1p, ko, 12288); STG2(b1p, ko + 32, 20480); }
    BARRIER();
    LGKM0();
    __builtin_amdgcn_s_setprio(1);
#pragma unroll
    for (int s = 0; s < 2; ++s)
#pragma unroll
      for (int mi = 0; mi < 4; ++mi)
#pragma unroll
        for (int ni = 0; ni < 2; ++ni)
          MFMA(accu[mi][ni], a[mi][s], bu[ni][s]);
    __builtin_amdgcn_s_setprio(0);
    if (!lastt) { VMCNT(2); }   // A' + Bh0' ready for next P0; Bh1' stays in flight
    BARRIER();
  }
#undef STG2

  const int rq = (lane >> 4) * 4, cl = lane & 15;
#pragma unroll
  for (int mi = 0; mi < 4; ++mi)
#pragma unroll
    for (int r = 0; r < 4; ++r) {
      int grow = m0 + wm + mi * 16 + rq + r;
      bf16* orow = h2 + (size_t)grow * Cn + n0;
#pragma unroll
      for (int ni = 0; ni < 2; ++ni) {
        orow[wnv + ni * 16 + cl]       = (bf16)accg[mi][ni][r];
        orow[128 + wnv + ni * 16 + cl] = (bf16)accu[mi][ni][r];
      }
    }
}

// ---------------- combine: out[t] = h2[r0(t)] + h2[r1(t)] ---------------------
__global__ __launch_bounds__(256) void combine_kernel(
    const bf16* __restrict__ h2, const int* __restrict__ inv_rows,
    float* __restrict__ out)
{
  int t = blockIdx.x;
  int r0 = inv_rows[2 * t], r1 = inv_rows[2 * t + 1];
  int c = threadIdx.x * 4;
  bf16x4 a = *(const bf16x4*)(h2 + (size_t)r0 * Cn + c);
  bf16x4 b = *(const bf16x4*)(h2 + (size_t)r1 * Cn + c);
  float4 v;
  v.x = (float)a[0] + (float)b[0];
  v.y = (float)a[1] + (float)b[1];
  v.z = (float)a[2] + (float)b[2];
  v.w = (float)a[3] + (float)b[3];
  *(float4*)(out + (size_t)t * Cn + c) = v;
}

// ---------------- host launch ------------------------------------------------
extern "C" void kernel_launch(void* const* d_in, const int* in_sizes, int n_in,
                              void* d_out, int out_size, void* d_ws, size_t ws_size,
                              hipStream_t stream)
{
  const float* x     = (const float*)d_in[0];
  const float* wgate = (const float*)d_in[1];
  const float* wg    = (const float*)d_in[2];
  const float* wu    = (const float*)d_in[3];
  const float* wd    = (const float*)d_in[4];

  char* ws = (char*)d_ws;
  int* counts = (int*)ws;
  int* fill   = counts + 8;
  int* off    = fill + 8;
  size_t o = 256;
  int*   topk_i   = (int*)(ws + o);   o += (size_t)Tn * 2 * 4;
  float* topk_w   = (float*)(ws + o); o += (size_t)Tn * 2 * 4;
  int*   tok_list = (int*)(ws + o);   o += (size_t)MAXROWS * 4;
  float* wgt_list = (float*)(ws + o); o += (size_t)MAXROWS * 4;
  int*   inv_rows = (int*)(ws + o);   o += (size_t)Tn * 2 * 4;
  o = (o + 255) & ~(size_t)255;
  const size_t WSZ = (size_t)En * Fn * Cn;
  bf16* wgT = (bf16*)(ws + o); o += WSZ * 2;
  bf16* wuT = (bf16*)(ws + o); o += WSZ * 2;
  bf16* wdT = (bf16*)(ws + o); o += WSZ * 2;
  bf16* xg  = (bf16*)(ws + o); o += (size_t)MAXROWS * Cn * 2;
  bf16* h2  = (bf16*)(ws + o); o += (size_t)MAXROWS * Cn * 2;
  bf16* h   = (bf16*)(ws + o);

  size_t havail = ws_size > o ? ws_size - o : 0;
  long crows = (long)(havail / ((size_t)Fn * 2));
  crows &= ~(long)255;
  if (crows > MAXROWS) crows = MAXROWS;
  if (crows < 256) crows = 256;
  const int chunk_rows = (int)crows;
  const int nch = (MAXROWS + chunk_rows - 1) / chunk_rows;

  hipMemsetAsync(counts, 0, 256, stream);
  hipMemsetAsync(tok_list, 0xFF, (size_t)MAXROWS * 4, stream);

  transpose_cvt<<<dim3(Cn / 64, Fn / 64, En), 256, 0, stream>>>(wg, wgT, Cn, Fn);
  transpose_cvt<<<dim3(Cn / 64, Fn / 64, En), 256, 0, stream>>>(wu, wuT, Cn, Fn);
  transpose_cvt<<<dim3(Fn / 64, Cn / 64, En), 256, 0, stream>>>(wd, wdT, Fn, Cn);

  gate_kernel<<<Tn / 4, 256, 0, stream>>>(x, wgate, topk_i, topk_w, counts);
  offsets_kernel<<<1, 64, 0, stream>>>(counts, fill, off);
  scatter_kernel<<<Tn / 256, 256, 0, stream>>>(topk_i, topk_w, fill, tok_list, wgt_list, inv_rows);
  gather_x<<<MAXROWS, 256, 0, stream>>>(x, tok_list, xg);

  const int mt = chunk_rows / 256;
  for (int c = 0; c < nch; ++c) {
    int row_lo = c * chunk_rows;
    gemm1_kernel<<<dim3((Fn + 127) / 128, mt), 512, 0, stream>>>(
        xg, wgT, wuT, off, counts, wgt_list, h, row_lo);
    gemm2_kernel<<<dim3(Cn / 256, chunk_rows / 128), 512, 0, stream>>>(
        h, wdT, off, h2, row_lo);
  }
  combine_kernel<<<Tn, 256, 0, stream>>>(h2, inv_rows, (float*)d_out);
}

// Round 2
// 767.877 us; speedup vs baseline: 1.0605x; 1.0234x over previous
//
#include <hip/hip_runtime.h>

#define Tn      8192
#define Cn      1024
#define En      8
#define Fn      2752
#define MAXROWS 18432
#define NT1     32      // Cn/32 K-tiles for gemm1
#define NT2     86      // Fn/32 K-tiles for gemm2

typedef __bf16 bf16;
typedef bf16  bf16x8 __attribute__((ext_vector_type(8)));
typedef bf16  bf16x4 __attribute__((ext_vector_type(4)));
typedef float f32x4  __attribute__((ext_vector_type(4)));

__device__ __forceinline__ void gload16(const bf16* g, bf16* l) {
  __builtin_amdgcn_global_load_lds(
      (const __attribute__((address_space(1))) unsigned int*)g,
      (__attribute__((address_space(3))) unsigned int*)l, 16, 0, 0);
}

#define BARRIER() __builtin_amdgcn_s_barrier()
#define VMCNT(N)  asm volatile("s_waitcnt vmcnt(" #N ")" ::: "memory")
#define MFMA(d, va, vb) d = __builtin_amdgcn_mfma_f32_16x16x32_bf16(va, vb, d, 0, 0, 0)

// bijective XCD-chunk swizzle (m204 form): consecutive remapped ids land on
// the same XCD -> n-fast walk shares A-panels within one XCD's L2.
__device__ __forceinline__ int xcd_swz(int flat, int nwg) {
  int xcd = flat & 7, loc = flat >> 3;
  int q = nwg >> 3, r = nwg & 7;
  return (xcd < r ? xcd * (q + 1) : r * (q + 1) + (xcd - r) * q) + loc;
}

// ---------------- gating ------------------------------------------------------
__global__ __launch_bounds__(256) void gate_kernel(
    const float* __restrict__ x, const float* __restrict__ wgate,
    int* __restrict__ topk_i, float* __restrict__ topk_w, int* __restrict__ counts)
{
  int lane = threadIdx.x & 63;
  int wid  = threadIdx.x >> 6;
  int t = blockIdx.x * 4 + wid;
  const float* xr = x + (size_t)t * Cn;
  float acc[En];
#pragma unroll
  for (int e = 0; e < En; ++e) acc[e] = 0.f;
  for (int c = lane; c < Cn; c += 64) {
    float xv = xr[c];
#pragma unroll
    for (int e = 0; e < En; ++e) acc[e] = fmaf(xv, wgate[e * Cn + c], acc[e]);
  }
#pragma unroll
  for (int e = 0; e < En; ++e) {
#pragma unroll
    for (int o = 32; o > 0; o >>= 1) acc[e] += __shfl_xor(acc[e], o, 64);
  }
  if (lane == 0) {
    float mx = acc[0];
#pragma unroll
    for (int e = 1; e < En; ++e) mx = fmaxf(mx, acc[e]);
    float p[En], Z = 0.f;
#pragma unroll
    for (int e = 0; e < En; ++e) { p[e] = __expf(acc[e] - mx); Z += p[e]; }
    int i0 = 0;
#pragma unroll
    for (int e = 1; e < En; ++e) if (p[e] > p[i0]) i0 = e;
    int i1 = (i0 == 0) ? 1 : 0;
#pragma unroll
    for (int e = 0; e < En; ++e) if (e != i0 && p[e] > p[i1]) i1 = e;
    float s0 = p[i0] / Z, s1 = p[i1] / Z;
    float inv = 1.f / (s0 + s1 + 1e-9f);
    topk_i[2 * t] = i0;       topk_i[2 * t + 1] = i1;
    topk_w[2 * t] = s0 * inv; topk_w[2 * t + 1] = s1 * inv;
    atomicAdd(&counts[i0], 1);
    atomicAdd(&counts[i1], 1);
  }
}

__global__ void offsets_kernel(const int* __restrict__ counts,
                               int* __restrict__ fill, int* __restrict__ off)
{
  if (threadIdx.x == 0 && blockIdx.x == 0) {
    int o = 0;
    for (int e = 0; e < En; ++e) {
      off[e]  = o;
      fill[e] = o;
      o += (counts[e] + 255) & ~255;   // 256-row expert padding
    }
    off[En] = o;
  }
}

__global__ __launch_bounds__(256) void scatter_kernel(
    const int* __restrict__ topk_i, const float* __restrict__ topk_w,
    int* __restrict__ fill, int* __restrict__ tok_list, float* __restrict__ wgt_list,
    int* __restrict__ inv_rows)
{
  int t = blockIdx.x * 256 + threadIdx.x;
#pragma unroll
  for (int j = 0; j < 2; ++j) {
    int e = topk_i[2 * t + j];
    int pos = atomicAdd(&fill[e], 1);
    tok_list[pos] = t;
    wgt_list[pos] = topk_w[2 * t + j];
    inv_rows[2 * t + j] = pos;
  }
}

__global__ __launch_bounds__(256) void gather_x(
    const float* __restrict__ x, const int* __restrict__ tok_list, bf16* __restrict__ xg)
{
  int row = blockIdx.x;
  int tok = tok_list[row];
  int c = threadIdx.x * 4;
  float4 v = make_float4(0.f, 0.f, 0.f, 0.f);
  if (tok >= 0) v = *(const float4*)(x + (size_t)tok * Cn + c);
  bf16x4 pv;
  pv[0] = (bf16)v.x; pv[1] = (bf16)v.y; pv[2] = (bf16)v.z; pv[3] = (bf16)v.w;
  *(bf16x4*)(xg + (size_t)row * Cn + c) = pv;
}

// ---------------- fast transpose + fp32->bf16 ---------------------------------
__global__ __launch_bounds__(256) void transpose_cvt(
    const float* __restrict__ src, bf16* __restrict__ dst, int M, int N)
{
  __shared__ float L[64][65];
  src += (size_t)blockIdx.z * M * N;
  dst += (size_t)blockIdx.z * M * N;
  const int bm = blockIdx.x * 64;
  const int bn = blockIdx.y * 64;
  const int tid = threadIdx.x;
  const int mr = tid >> 4, nseg = tid & 15;
#pragma unroll
  for (int p = 0; p < 4; ++p) {
    int m = p * 16 + mr;
    float4 v = *(const float4*)(src + (size_t)(bm + m) * N + bn + nseg * 4);
    L[nseg * 4 + 0][m] = v.x;
    L[nseg * 4 + 1][m] = v.y;
    L[nseg * 4 + 2][m] = v.z;
    L[nseg * 4 + 3][m] = v.w;
  }
  __syncthreads();
  const int nr = tid >> 3, mseg = tid & 7;
#pragma unroll
  for (int q = 0; q < 2; ++q) {
    int n = q * 32 + nr;
    bf16x8 w;
#pragma unroll
    for (int j = 0; j < 8; ++j) w[j] = (bf16)L[n][mseg * 8 + j];
    *(bf16x8*)(dst + (size_t)(bn + n) * M + bm + mseg * 8) = w;
  }
}

// LDS K-tile layout (BK=32, 64B rows = 4 x 16B slots):
//   LDS[row][slot] = G[row][slot ^ ((row>>1)&3)]   -> conflict-free b128 frag reads
// staging lane: row = tid>>2, gseg = (tid&3) ^ ((tid>>3)&3)
// frag read:   slot = q ^ ((fr>>1)&3),  q = lane>>4, fr = lane&15

// ---------------- GEMM1: h = wgt * silu(xg@wgT') * (xg@wuT') ------------------
// block 256 x 64 real cols (gate+up), BK=32, 4 waves (wave = 128 x 32 x {g,u}),
// dbuf 48KB LDS -> 2 blocks/CU. 2 phases/K-tile, counted vmcnt, no lgkm drains.
// grid (pre-swizzle): x = n (43, fast), y = m (rows/256).
__global__ __launch_bounds__(256, 2) void gemm1_kernel(
    const bf16* __restrict__ xg, const bf16* __restrict__ wgT, const bf16* __restrict__ wuT,
    const int* __restrict__ off, const int* __restrict__ counts,
    const float* __restrict__ wgt_list, bf16* __restrict__ h, int row_lo)
{
  const int gdx = gridDim.x;
  const int nwg = gdx * gridDim.y;
  const int s = xcd_swz(blockIdx.y * gdx + blockIdx.x, nwg);
  const int bx = s % gdx, by = s / gdx;

  const int m0 = row_lo + by * 256;
  if (m0 >= off[En]) return;
  int e = 0;
  while (off[e + 1] <= m0) ++e;
  const int base = off[e], cnt = counts[e];
  const int n0 = bx * 64;

  // buffer layout (elements): A [256r][32] @0 (8192) ; Bg [64r][32] @8192 ; Bu @10240
  __shared__ bf16 sm[2][12288];   // 48 KB

  const int tid = threadIdx.x;
  const int lane = tid & 63, wid = tid >> 6;
  const int wm  = (wid & 1) * 128;        // wave m-half
  const int wnv = (wid >> 1) * 32;        // wave col-half (real F cols)
  const int fr = lane & 15, q = lane >> 4;
  const int lrow = tid >> 2;              // staging row 0..63
  const int gseg = (tid & 3) ^ ((tid >> 3) & 3);
  const int tt = (q ^ ((fr >> 1) & 3)) * 8;

  const bf16* wge = wgT + (size_t)e * ((size_t)Fn * Cn);
  const bf16* wue = wuT + (size_t)e * ((size_t)Fn * Cn);
  const bf16* ag0 = xg + (size_t)(m0 + lrow) * Cn + gseg * 8;
  const bf16* ag1 = ag0 + (size_t)64 * Cn;
  const bf16* ag2 = ag0 + (size_t)128 * Cn;
  const bf16* ag3 = ag0 + (size_t)192 * Cn;
  const bf16* bgp = wge + (size_t)(n0 + lrow) * Cn + gseg * 8;
  const bf16* bup = wue + (size_t)(n0 + lrow) * Cn + gseg * 8;

  f32x4 accg[8][2], accu[8][2];
#pragma unroll
  for (int mi = 0; mi < 8; ++mi)
#pragma unroll
    for (int ni = 0; ni < 2; ++ni) { accg[mi][ni] = (f32x4)(0.f); accu[mi][ni] = (f32x4)(0.f); }

#define STG1(SRC, KOFF, DOFF) gload16((SRC) + (KOFF), Nx + (DOFF) + tid * 8)

  // prologue: stage tile 0 (issue order = {A0,A1,A2,A3,Bg,Bu})
  {
    bf16* Nx = &sm[0][0];
    STG1(ag0, 0, 0);    STG1(ag1, 0, 2048);
    STG1(ag2, 0, 4096); STG1(ag3, 0, 6144);
    STG1(bgp, 0, 8192); STG1(bup, 0, 10240);
  }
  VMCNT(1);            // A,Bg complete; Bu may be in flight
  BARRIER();

  for (int kt = 0; kt < NT1; ++kt) {
    const int b = kt & 1;
    const bf16* S = &sm[b][0];
    bf16* Nx = &sm[b ^ 1][0];
    const bool lastt = (kt == NT1 - 1);
    const int ko = (kt + 1) * 32;

    bf16x8 a[8], bg[2], bu[2];

    // ---- P0: read a + bg ; stage {A0',A1',A2'} ; MFMA gate
#pragma unroll
    for (int mi = 0; mi < 8; ++mi)
      a[mi] = *(const bf16x8*)(S + (wm + mi * 16 + fr) * 32 + tt);
#pragma unroll
    for (int ni = 0; ni < 2; ++ni)
      bg[ni] = *(const bf16x8*)(S + 8192 + (wnv + ni * 16 + fr) * 32 + tt);
    if (!lastt) { STG1(ag0, ko, 0); STG1(ag1, ko, 2048); STG1(ag2, ko, 4096); }
    BARRIER();
    __builtin_amdgcn_s_setprio(1);
#pragma unroll
    for (int mi = 0; mi < 8; ++mi)
#pragma unroll
      for (int ni = 0; ni < 2; ++ni)
        MFMA(accg[mi][ni], a[mi], bg[ni]);
    __builtin_amdgcn_s_setprio(0);
    if (lastt) { VMCNT(0); } else { VMCNT(3); }   // Bu(kt) landed for P1
    BARRIER();

    // ---- P1: read bu ; stage {A3',Bg',Bu'} ; MFMA up
#pragma unroll
    for (int ni = 0; ni < 2; ++ni)
      bu[ni] = *(const bf16x8*)(S + 10240 + (wnv + ni * 16 + fr) * 32 + tt);
    if (!lastt) { STG1(ag3, ko, 6144); STG1(bgp, ko, 8192); STG1(bup, ko, 10240); }
    BARRIER();
    __builtin_amdgcn_s_setprio(1);
#pragma unroll
    for (int mi = 0; mi < 8; ++mi)
#pragma unroll
      for (int ni = 0; ni < 2; ++ni)
        MFMA(accu[mi][ni], a[mi], bu[ni]);
    __builtin_amdgcn_s_setprio(0);
    if (!lastt) { VMCNT(1); }   // A0'..A3',Bg' landed for next P0; Bu' in flight
    BARRIER();
  }
#undef STG1

  // epilogue: h = wgt * u * silu(g)
  const int rq = (lane >> 4) * 4, cl = lane & 15;
#pragma unroll
  for (int mi = 0; mi < 8; ++mi) {
#pragma unroll
    for (int r = 0; r < 4; ++r) {
      int grow = m0 + wm + mi * 16 + rq + r;
      float w = (grow - base < cnt) ? wgt_list[grow] : 0.f;
      bf16* hr = h + (size_t)(grow - row_lo) * Fn + n0;
#pragma unroll
      for (int ni = 0; ni < 2; ++ni) {
        float g = accg[mi][ni][r], u = accu[mi][ni][r];
        hr[wnv + ni * 16 + cl] = (bf16)(w * u * (g / (1.f + __expf(-g))));
      }
    }
  }
}

// ---------------- GEMM2: h2[row] = h[row] @ wdT' ------------------------------
// block 128 x 256, BK=32, 4 waves (wave = 64 x 128), dbuf 48KB -> 2 blocks/CU.
// 2 phases/K-tile, counted vmcnt. grid (pre-swizzle): x = n (4, fast), y = m.
__global__ __launch_bounds__(256, 2) void gemm2_kernel(
    const bf16* __restrict__ h, const bf16* __restrict__ wdT,
    const int* __restrict__ off, bf16* __restrict__ h2, int row_lo)
{
  const int gdx = gridDim.x;
  const int nwg = gdx * gridDim.y;
  const int s = xcd_swz(blockIdx.y * gdx + blockIdx.x, nwg);
  const int bx = s % gdx, by = s / gdx;

  const int m0 = row_lo + by * 128;
  if (m0 >= off[En]) return;
  int e = 0;
  while (off[e + 1] <= m0) ++e;
  const int n0 = bx * 256;

  // buffer layout (elements): A [128r][32] @0 (4096) ; B [256r][32] @4096 (8192)
  __shared__ bf16 sm[2][12288];   // 48 KB

  const int tid = threadIdx.x;
  const int lane = tid & 63, wid = tid >> 6;
  const int wrow = (wid & 1) * 64;        // wave m-half
  const int wcol = (wid >> 1) * 128;      // wave n-half
  const int fr = lane & 15, q = lane >> 4;
  const int lrow = tid >> 2;              // staging row 0..63
  const int gseg = (tid & 3) ^ ((tid >> 3) & 3);
  const int tt = (q ^ ((fr >> 1) & 3)) * 8;

  const bf16* wde = wdT + (size_t)e * ((size_t)Cn * Fn);
  const bf16* a0p = h   + (size_t)(m0 - row_lo + lrow) * Fn + gseg * 8;
  const bf16* a1p = a0p + (size_t)64 * Fn;
  const bf16* b0p = wde + (size_t)(n0 + lrow) * Fn + gseg * 8;
  const bf16* b1p = b0p + (size_t)64 * Fn;
  const bf16* b2p = b0p + (size_t)128 * Fn;
  const bf16* b3p = b0p + (size_t)192 * Fn;

  f32x4 acc[4][8];
#pragma unroll
  for (int mi = 0; mi < 4; ++mi)
#pragma unroll
    for (int ni = 0; ni < 8; ++ni) acc[mi][ni] = (f32x4)(0.f);

#define STG2(SRC, KOFF, DOFF) gload16((SRC) + (KOFF), Nx + (DOFF) + tid * 8)

  // prologue: issue order = {A0,A1,B0,B2, B1,B3}
  {
    bf16* Nx = &sm[0][0];
    STG2(a0p, 0, 0);    STG2(a1p, 0, 2048);
    STG2(b0p, 0, 4096); STG2(b2p, 0, 8192);
    STG2(b1p, 0, 6144); STG2(b3p, 0, 10240);
  }
  VMCNT(2);            // A + B-low-halves complete; B1,B3 may be in flight
  BARRIER();

  for (int kt = 0; kt < NT2; ++kt) {
    const int b = kt & 1;
    const bf16* S = &sm[b][0];
    bf16* Nx = &sm[b ^ 1][0];
    const bool lastt = (kt == NT2 - 1);
    const int ko = (kt + 1) * 32;

    bf16x8 a[4], bl[4], bh[4];

    // ---- P0: read a + b(cols wcol..wcol+63) ; stage {A0',A1',B0',B2'} ; MFMA low
#pragma unroll
    for (int mi = 0; mi < 4; ++mi)
      a[mi] = *(const bf16x8*)(S + (wrow + mi * 16 + fr) * 32 + tt);
#pragma unroll
    for (int ni = 0; ni < 4; ++ni)
      bl[ni] = *(const bf16x8*)(S + 4096 + (wcol + ni * 16 + fr) * 32 + tt);
    if (!lastt) { STG2(a0p, ko, 0); STG2(a1p, ko, 2048); STG2(b0p, ko, 4096); STG2(b2p, ko, 8192); }
    BARRIER();
    __builtin_amdgcn_s_setprio(1);
#pragma unroll
    for (int mi = 0; mi < 4; ++mi)
#pragma unroll
      for (int ni = 0; ni < 4; ++ni)
        MFMA(acc[mi][ni], a[mi], bl[ni]);
    __builtin_amdgcn_s_setprio(0);
    if (lastt) { VMCNT(0); } else { VMCNT(4); }   // B1,B3(kt) landed for P1
    BARRIER();

    // ---- P1: read b(cols wcol+64..wcol+127) ; stage {B1',B3'} ; MFMA high
#pragma unroll
    for (int ni = 0; ni < 4; ++ni)
      bh[ni] = *(const bf16x8*)(S + 4096 + (wcol + 64 + ni * 16 + fr) * 32 + tt);
    if (!lastt) { STG2(b1p, ko, 6144); STG2(b3p, ko, 10240); }
    BARRIER();
    __builtin_amdgcn_s_setprio(1);
#pragma unroll
    for (int mi = 0; mi < 4; ++mi)
#pragma unroll
      for (int ni = 0; ni < 4; ++ni)
        MFMA(acc[mi][4 + ni], a[mi], bh[ni]);
    __builtin_amdgcn_s_setprio(0);
    if (!lastt) { VMCNT(2); }   // A',B0',B2' landed for next P0; B1',B3' in flight
    BARRIER();
  }
#undef STG2

  const int rq = (lane >> 4) * 4, cl = lane & 15;
#pragma unroll
  for (int mi = 0; mi < 4; ++mi) {
#pragma unroll
    for (int r = 0; r < 4; ++r) {
      int grow = m0 + wrow + mi * 16 + rq + r;
      bf16* orow = h2 + (size_t)grow * Cn + n0;
#pragma unroll
      for (int ni = 0; ni < 8; ++ni)
        orow[wcol + ni * 16 + cl] = (bf16)acc[mi][ni][r];
    }
  }
}

// ---------------- combine: out[t] = h2[r0(t)] + h2[r1(t)] ---------------------
__global__ __launch_bounds__(256) void combine_kernel(
    const bf16* __restrict__ h2, const int* __restrict__ inv_rows,
    float* __restrict__ out)
{
  int t = blockIdx.x;
  int r0 = inv_rows[2 * t], r1 = inv_rows[2 * t + 1];
  int c = threadIdx.x * 4;
  bf16x4 a = *(const bf16x4*)(h2 + (size_t)r0 * Cn + c);
  bf16x4 b = *(const bf16x4*)(h2 + (size_t)r1 * Cn + c);
  float4 v;
  v.x = (float)a[0] + (float)b[0];
  v.y = (float)a[1] + (float)b[1];
  v.z = (float)a[2] + (float)b[2];
  v.w = (float)a[3] + (float)b[3];
  *(float4*)(out + (size_t)t * Cn + c) = v;
}

// ---------------- host launch ------------------------------------------------
extern "C" void kernel_launch(void* const* d_in, const int* in_sizes, int n_in,
                              void* d_out, int out_size, void* d_ws, size_t ws_size,
                              hipStream_t stream)
{
  const float* x     = (const float*)d_in[0];
  const float* wgate = (const float*)d_in[1];
  const float* wg    = (const float*)d_in[2];
  const float* wu    = (const float*)d_in[3];
  const float* wd    = (const float*)d_in[4];

  char* ws = (char*)d_ws;
  int* counts = (int*)ws;
  int* fill   = counts + 8;
  int* off    = fill + 8;
  size_t o = 256;
  int*   topk_i   = (int*)(ws + o);   o += (size_t)Tn * 2 * 4;
  float* topk_w   = (float*)(ws + o); o += (size_t)Tn * 2 * 4;
  int*   tok_list = (int*)(ws + o);   o += (size_t)MAXROWS * 4;
  float* wgt_list = (float*)(ws + o); o += (size_t)MAXROWS * 4;
  int*   inv_rows = (int*)(ws + o);   o += (size_t)Tn * 2 * 4;
  o = (o + 255) & ~(size_t)255;
  const size_t WSZ = (size_t)En * Fn * Cn;
  bf16* wgT = (bf16*)(ws + o); o += WSZ * 2;
  bf16* wuT = (bf16*)(ws + o); o += WSZ * 2;
  bf16* wdT = (bf16*)(ws + o); o += WSZ * 2;
  bf16* xg  = (bf16*)(ws + o); o += (size_t)MAXROWS * Cn * 2;
  bf16* h2  = (bf16*)(ws + o); o += (size_t)MAXROWS * Cn * 2;
  bf16* h   = (bf16*)(ws + o);

  size_t havail = ws_size > o ? ws_size - o : 0;
  long crows = (long)(havail / ((size_t)Fn * 2));
  crows &= ~(long)255;
  if (crows > MAXROWS) crows = MAXROWS;
  if (crows < 256) crows = 256;
  const int chunk_rows = (int)crows;
  const int nch = (MAXROWS + chunk_rows - 1) / chunk_rows;

  hipMemsetAsync(counts, 0, 256, stream);
  hipMemsetAsync(tok_list, 0xFF, (size_t)MAXROWS * 4, stream);

  transpose_cvt<<<dim3(Cn / 64, Fn / 64, En), 256, 0, stream>>>(wg, wgT, Cn, Fn);
  transpose_cvt<<<dim3(Cn / 64, Fn / 64, En), 256, 0, stream>>>(wu, wuT, Cn, Fn);
  transpose_cvt<<<dim3(Fn / 64, Cn / 64, En), 256, 0, stream>>>(wd, wdT, Fn, Cn);

  gate_kernel<<<Tn / 4, 256, 0, stream>>>(x, wgate, topk_i, topk_w, counts);
  offsets_kernel<<<1, 64, 0, stream>>>(counts, fill, off);
  scatter_kernel<<<Tn / 256, 256, 0, stream>>>(topk_i, topk_w, fill, tok_list, wgt_list, inv_rows);
  gather_x<<<MAXROWS, 256, 0, stream>>>(x, tok_list, xg);

  for (int c = 0; c < nch; ++c) {
    int row_lo = c * chunk_rows;
    gemm1_kernel<<<dim3(Fn / 64, chunk_rows / 256), 256, 0, stream>>>(
        xg, wgT, wuT, off, counts, wgt_list, h, row_lo);
    gemm2_kernel<<<dim3(Cn / 256, chunk_rows / 128), 256, 0, stream>>>(
        h, wdT, off, h2, row_lo);
  }
  combine_kernel<<<Tn, 256, 0, stream>>>(h2, inv_rows, (float*)d_out);
}

// Round 3
// 743.776 us; speedup vs baseline: 1.0948x; 1.0324x over previous
//
#include <hip/hip_runtime.h>

#define Tn      8192
#define Cn      1024
#define En      8
#define Fn      2752
#define MAXROWS 18432
#define NT1     32      // Cn/32 K-tiles for gemm1
#define NT2     86      // Fn/32 K-tiles for gemm2

typedef __bf16 bf16;
typedef bf16  bf16x8 __attribute__((ext_vector_type(8)));
typedef bf16  bf16x4 __attribute__((ext_vector_type(4)));
typedef float f32x4  __attribute__((ext_vector_type(4)));

__device__ __forceinline__ void gload16(const bf16* g, bf16* l) {
  __builtin_amdgcn_global_load_lds(
      (const __attribute__((address_space(1))) unsigned int*)g,
      (__attribute__((address_space(3))) unsigned int*)l, 16, 0, 0);
}

#define BARRIER() __builtin_amdgcn_s_barrier()
#define VMCNT(N)  asm volatile("s_waitcnt vmcnt(" #N ")" ::: "memory")
#define MFMA(d, va, vb) d = __builtin_amdgcn_mfma_f32_16x16x32_bf16(va, vb, d, 0, 0, 0)

// bijective XCD-chunk swizzle: consecutive remapped ids land on the same XCD.
__device__ __forceinline__ int xcd_swz(int flat, int nwg) {
  int xcd = flat & 7, loc = flat >> 3;
  int q = nwg >> 3, r = nwg & 7;
  return (xcd < r ? xcd * (q + 1) : r * (q + 1) + (xcd - r) * q) + loc;
}

// ---------------- gating ------------------------------------------------------
__global__ __launch_bounds__(256) void gate_kernel(
    const float* __restrict__ x, const float* __restrict__ wgate,
    int* __restrict__ topk_i, float* __restrict__ topk_w, int* __restrict__ counts)
{
  int lane = threadIdx.x & 63;
  int wid  = threadIdx.x >> 6;
  int t = blockIdx.x * 4 + wid;
  const float* xr = x + (size_t)t * Cn;
  float acc[En];
#pragma unroll
  for (int e = 0; e < En; ++e) acc[e] = 0.f;
  for (int c = lane; c < Cn; c += 64) {
    float xv = xr[c];
#pragma unroll
    for (int e = 0; e < En; ++e) acc[e] = fmaf(xv, wgate[e * Cn + c], acc[e]);
  }
#pragma unroll
  for (int e = 0; e < En; ++e) {
#pragma unroll
    for (int o = 32; o > 0; o >>= 1) acc[e] += __shfl_xor(acc[e], o, 64);
  }
  if (lane == 0) {
    float mx = acc[0];
#pragma unroll
    for (int e = 1; e < En; ++e) mx = fmaxf(mx, acc[e]);
    float p[En], Z = 0.f;
#pragma unroll
    for (int e = 0; e < En; ++e) { p[e] = __expf(acc[e] - mx); Z += p[e]; }
    int i0 = 0;
#pragma unroll
    for (int e = 1; e < En; ++e) if (p[e] > p[i0]) i0 = e;
    int i1 = (i0 == 0) ? 1 : 0;
#pragma unroll
    for (int e = 0; e < En; ++e) if (e != i0 && p[e] > p[i1]) i1 = e;
    float s0 = p[i0] / Z, s1 = p[i1] / Z;
    float inv = 1.f / (s0 + s1 + 1e-9f);
    topk_i[2 * t] = i0;       topk_i[2 * t + 1] = i1;
    topk_w[2 * t] = s0 * inv; topk_w[2 * t + 1] = s1 * inv;
    atomicAdd(&counts[i0], 1);
    atomicAdd(&counts[i1], 1);
  }
}

__global__ void offsets_kernel(const int* __restrict__ counts,
                               int* __restrict__ fill, int* __restrict__ off)
{
  if (threadIdx.x == 0 && blockIdx.x == 0) {
    int o = 0;
    for (int e = 0; e < En; ++e) {
      off[e]  = o;
      fill[e] = o;
      o += (counts[e] + 255) & ~255;   // 256-row expert padding
    }
    off[En] = o;
  }
}

__global__ __launch_bounds__(256) void scatter_kernel(
    const int* __restrict__ topk_i, const float* __restrict__ topk_w,
    int* __restrict__ fill, int* __restrict__ tok_list, float* __restrict__ wgt_list,
    int* __restrict__ inv_rows)
{
  int t = blockIdx.x * 256 + threadIdx.x;
#pragma unroll
  for (int j = 0; j < 2; ++j) {
    int e = topk_i[2 * t + j];
    int pos = atomicAdd(&fill[e], 1);
    tok_list[pos] = t;
    wgt_list[pos] = topk_w[2 * t + j];
    inv_rows[2 * t + j] = pos;
  }
}

__global__ __launch_bounds__(256) void gather_x(
    const float* __restrict__ x, const int* __restrict__ tok_list, bf16* __restrict__ xg)
{
  int row = blockIdx.x;
  int tok = tok_list[row];
  int c = threadIdx.x * 4;
  float4 v = make_float4(0.f, 0.f, 0.f, 0.f);
  if (tok >= 0) v = *(const float4*)(x + (size_t)tok * Cn + c);
  bf16x4 pv;
  pv[0] = (bf16)v.x; pv[1] = (bf16)v.y; pv[2] = (bf16)v.z; pv[3] = (bf16)v.w;
  *(bf16x4*)(xg + (size_t)row * Cn + c) = pv;
}

// ---------------- fast transpose + fp32->bf16 ---------------------------------
__global__ __launch_bounds__(256) void transpose_cvt(
    const float* __restrict__ src, bf16* __restrict__ dst, int M, int N)
{
  __shared__ float L[64][65];
  src += (size_t)blockIdx.z * M * N;
  dst += (size_t)blockIdx.z * M * N;
  const int bm = blockIdx.x * 64;
  const int bn = blockIdx.y * 64;
  const int tid = threadIdx.x;
  const int mr = tid >> 4, nseg = tid & 15;
#pragma unroll
  for (int p = 0; p < 4; ++p) {
    int m = p * 16 + mr;
    float4 v = *(const float4*)(src + (size_t)(bm + m) * N + bn + nseg * 4);
    L[nseg * 4 + 0][m] = v.x;
    L[nseg * 4 + 1][m] = v.y;
    L[nseg * 4 + 2][m] = v.z;
    L[nseg * 4 + 3][m] = v.w;
  }
  __syncthreads();
  const int nr = tid >> 3, mseg = tid & 7;
#pragma unroll
  for (int q = 0; q < 2; ++q) {
    int n = q * 32 + nr;
    bf16x8 w;
#pragma unroll
    for (int j = 0; j < 8; ++j) w[j] = (bf16)L[n][mseg * 8 + j];
    *(bf16x8*)(dst + (size_t)(bn + n) * M + bm + mseg * 8) = w;
  }
}

// LDS K-tile layout (BK=32, 64B rows = 4 x 16B slots):
//   LDS[row][slot] = G[row][slot ^ ((row>>1)&3)]   -> conflict-free b128 frag reads
// staging lane: row = tid>>2, gseg = (tid&3) ^ ((tid>>3)&3)
// frag read:   slot = q ^ ((fr>>1)&3),  q = lane>>4, fr = lane&15

// ---------------- GEMM1: h = wgt * silu(xg@wgT') * (xg@wuT') ------------------
// block 256 x 64 real cols (gate+up), BK=32, 4 waves, TRIPLE-buffered 72KB LDS
// (loads issued 2 K-tiles ahead -> ~1 K-tile of latency slack), 1 barrier/K-tile.
// grid (pre-swizzle): x = n (43, fast), y = m (rows/256).
__global__ __launch_bounds__(256, 2) void gemm1_kernel(
    const bf16* __restrict__ xg, const bf16* __restrict__ wgT, const bf16* __restrict__ wuT,
    const int* __restrict__ off, const int* __restrict__ counts,
    const float* __restrict__ wgt_list, bf16* __restrict__ h, int row_lo)
{
  const int gdx = gridDim.x;
  const int nwg = gdx * gridDim.y;
  const int s = xcd_swz(blockIdx.y * gdx + blockIdx.x, nwg);
  const int bx = s % gdx, by = s / gdx;

  const int m0 = row_lo + by * 256;
  if (m0 >= off[En]) return;
  int e = 0;
  while (off[e + 1] <= m0) ++e;
  const int base = off[e], cnt = counts[e];
  const int n0 = bx * 64;

  // per-buffer layout (elements): A [256r][32] @0 ; Bg [64r][32] @8192 ; Bu @10240
  __shared__ bf16 sm[3][12288];   // 72 KB

  const int tid = threadIdx.x;
  const int lane = tid & 63, wid = tid >> 6;
  const int wm  = (wid & 1) * 128;        // wave m-half
  const int wnv = (wid >> 1) * 32;        // wave col-half (real F cols)
  const int fr = lane & 15, q = lane >> 4;
  const int lrow = tid >> 2;              // staging row 0..63
  const int gseg = (tid & 3) ^ ((tid >> 3) & 3);
  const int tt = (q ^ ((fr >> 1) & 3)) * 8;

  const bf16* wge = wgT + (size_t)e * ((size_t)Fn * Cn);
  const bf16* wue = wuT + (size_t)e * ((size_t)Fn * Cn);
  const bf16* ag0 = xg + (size_t)(m0 + lrow) * Cn + gseg * 8;
  const bf16* ag1 = ag0 + (size_t)64 * Cn;
  const bf16* ag2 = ag0 + (size_t)128 * Cn;
  const bf16* ag3 = ag0 + (size_t)192 * Cn;
  const bf16* bgp = wge + (size_t)(n0 + lrow) * Cn + gseg * 8;
  const bf16* bup = wue + (size_t)(n0 + lrow) * Cn + gseg * 8;

  f32x4 accg[8][2], accu[8][2];
#pragma unroll
  for (int mi = 0; mi < 8; ++mi)
#pragma unroll
    for (int ni = 0; ni < 2; ++ni) { accg[mi][ni] = (f32x4)(0.f); accu[mi][ni] = (f32x4)(0.f); }

#define STG1(SRC, KOFF, DST, DOFF) gload16((SRC) + (KOFF), (DST) + (DOFF) + tid * 8)
#define ISSUE1(DST, KO) do { \
    STG1(ag0, KO, DST, 0);    STG1(ag1, KO, DST, 2048); \
    STG1(ag2, KO, DST, 4096); STG1(ag3, KO, DST, 6144); \
    STG1(bgp, KO, DST, 8192); STG1(bup, KO, DST, 10240); } while (0)

  // prologue: issue tiles 0 and 1; wait tile 0 (6 of tile 1 in flight)
  ISSUE1(&sm[0][0], 0);
  ISSUE1(&sm[1][0], 32);
  VMCNT(6);
  BARRIER();

  const bf16* Sc = &sm[0][0];   // current (tile kt)
  const bf16* Sn = &sm[1][0];   // next    (tile kt+1, landing)
  bf16*       Sf = &sm[2][0];   // far     (tile kt+2, being issued)

  for (int kt = 0; kt < NT1; ++kt) {
    bf16x8 a[8], bg[2], bu[2];
#pragma unroll
    for (int mi = 0; mi < 8; ++mi)
      a[mi] = *(const bf16x8*)(Sc + (wm + mi * 16 + fr) * 32 + tt);
#pragma unroll
    for (int ni = 0; ni < 2; ++ni) {
      bg[ni] = *(const bf16x8*)(Sc + 8192 + (wnv + ni * 16 + fr) * 32 + tt);
      bu[ni] = *(const bf16x8*)(Sc + 10240 + (wnv + ni * 16 + fr) * 32 + tt);
    }
    if (kt + 2 < NT1) ISSUE1(Sf, (kt + 2) * 32);

    __builtin_amdgcn_s_setprio(1);
#pragma unroll
    for (int mi = 0; mi < 8; ++mi)
#pragma unroll
      for (int ni = 0; ni < 2; ++ni) {
        MFMA(accg[mi][ni], a[mi], bg[ni]);
        MFMA(accu[mi][ni], a[mi], bu[ni]);
      }
    __builtin_amdgcn_s_setprio(0);

    if (kt < NT1 - 2)       { VMCNT(6); BARRIER(); }
    else if (kt == NT1 - 2) { VMCNT(0); BARRIER(); }
    // rotate buffers
    const bf16* t0 = Sc; Sc = Sn; Sn = Sf; Sf = (bf16*)t0;
  }
#undef ISSUE1
#undef STG1

  // epilogue: h = wgt * u * silu(g)
  const int rq = (lane >> 4) * 4, cl = lane & 15;
#pragma unroll
  for (int mi = 0; mi < 8; ++mi) {
#pragma unroll
    for (int r = 0; r < 4; ++r) {
      int grow = m0 + wm + mi * 16 + rq + r;
      float w = (grow - base < cnt) ? wgt_list[grow] : 0.f;
      bf16* hr = h + (size_t)(grow - row_lo) * Fn + n0;
#pragma unroll
      for (int ni = 0; ni < 2; ++ni) {
        float g = accg[mi][ni][r], u = accu[mi][ni][r];
        hr[wnv + ni * 16 + cl] = (bf16)(w * u * (g / (1.f + __expf(-g))));
      }
    }
  }
}

// ---------------- GEMM2: h2[row] = h[row] @ wdT' ------------------------------
// block 128 x 256, BK=32, 4 waves (wave = 64 x 128), triple-buffered 72KB LDS,
// loads 2 K-tiles ahead, 1 barrier/K-tile. grid (pre-swizzle): x = n (4), y = m.
__global__ __launch_bounds__(256, 2) void gemm2_kernel(
    const bf16* __restrict__ h, const bf16* __restrict__ wdT,
    const int* __restrict__ off, bf16* __restrict__ h2, int row_lo)
{
  const int gdx = gridDim.x;
  const int nwg = gdx * gridDim.y;
  const int s = xcd_swz(blockIdx.y * gdx + blockIdx.x, nwg);
  const int bx = s % gdx, by = s / gdx;

  const int m0 = row_lo + by * 128;
  if (m0 >= off[En]) return;
  int e = 0;
  while (off[e + 1] <= m0) ++e;
  const int n0 = bx * 256;

  // per-buffer layout (elements): A [128r][32] @0 ; B [256r][32] @4096
  __shared__ bf16 sm[3][12288];   // 72 KB

  const int tid = threadIdx.x;
  const int lane = tid & 63, wid = tid >> 6;
  const int wrow = (wid & 1) * 64;        // wave m-half
  const int wcol = (wid >> 1) * 128;      // wave n-half
  const int fr = lane & 15, q = lane >> 4;
  const int lrow = tid >> 2;              // staging row 0..63
  const int gseg = (tid & 3) ^ ((tid >> 3) & 3);
  const int tt = (q ^ ((fr >> 1) & 3)) * 8;

  const bf16* wde = wdT + (size_t)e * ((size_t)Cn * Fn);
  const bf16* a0p = h   + (size_t)(m0 - row_lo + lrow) * Fn + gseg * 8;
  const bf16* a1p = a0p + (size_t)64 * Fn;
  const bf16* b0p = wde + (size_t)(n0 + lrow) * Fn + gseg * 8;
  const bf16* b1p = b0p + (size_t)64 * Fn;
  const bf16* b2p = b0p + (size_t)128 * Fn;
  const bf16* b3p = b0p + (size_t)192 * Fn;

  f32x4 acc[4][8];
#pragma unroll
  for (int mi = 0; mi < 4; ++mi)
#pragma unroll
    for (int ni = 0; ni < 8; ++ni) acc[mi][ni] = (f32x4)(0.f);

#define STG2(SRC, KOFF, DST, DOFF) gload16((SRC) + (KOFF), (DST) + (DOFF) + tid * 8)
#define ISSUE2(DST, KO) do { \
    STG2(a0p, KO, DST, 0);    STG2(a1p, KO, DST, 2048); \
    STG2(b0p, KO, DST, 4096); STG2(b1p, KO, DST, 6144); \
    STG2(b2p, KO, DST, 8192); STG2(b3p, KO, DST, 10240); } while (0)

  ISSUE2(&sm[0][0], 0);
  ISSUE2(&sm[1][0], 32);
  VMCNT(6);
  BARRIER();

  const bf16* Sc = &sm[0][0];
  const bf16* Sn = &sm[1][0];
  bf16*       Sf = &sm[2][0];

  for (int kt = 0; kt < NT2; ++kt) {
    bf16x8 a[4], b[8];
#pragma unroll
    for (int mi = 0; mi < 4; ++mi)
      a[mi] = *(const bf16x8*)(Sc + (wrow + mi * 16 + fr) * 32 + tt);
#pragma unroll
    for (int ni = 0; ni < 8; ++ni)
      b[ni] = *(const bf16x8*)(Sc + 4096 + (wcol + ni * 16 + fr) * 32 + tt);
    if (kt + 2 < NT2) ISSUE2(Sf, (kt + 2) * 32);

    __builtin_amdgcn_s_setprio(1);
#pragma unroll
    for (int mi = 0; mi < 4; ++mi)
#pragma unroll
      for (int ni = 0; ni < 8; ++ni)
        MFMA(acc[mi][ni], a[mi], b[ni]);
    __builtin_amdgcn_s_setprio(0);

    if (kt < NT2 - 2)       { VMCNT(6); BARRIER(); }
    else if (kt == NT2 - 2) { VMCNT(0); BARRIER(); }
    const bf16* t0 = Sc; Sc = Sn; Sn = Sf; Sf = (bf16*)t0;
  }
#undef ISSUE2
#undef STG2

  const int rq = (lane >> 4) * 4, cl = lane & 15;
#pragma unroll
  for (int mi = 0; mi < 4; ++mi) {
#pragma unroll
    for (int r = 0; r < 4; ++r) {
      int grow = m0 + wrow + mi * 16 + rq + r;
      bf16* orow = h2 + (size_t)grow * Cn + n0;
#pragma unroll
      for (int ni = 0; ni < 8; ++ni)
        orow[wcol + ni * 16 + cl] = (bf16)acc[mi][ni][r];
    }
  }
}

// ---------------- combine: out[t] = h2[r0(t)] + h2[r1(t)] ---------------------
__global__ __launch_bounds__(256) void combine_kernel(
    const bf16* __restrict__ h2, const int* __restrict__ inv_rows,
    float* __restrict__ out)
{
  int t = blockIdx.x;
  int r0 = inv_rows[2 * t], r1 = inv_rows[2 * t + 1];
  int c = threadIdx.x * 4;
  bf16x4 a = *(const bf16x4*)(h2 + (size_t)r0 * Cn + c);
  bf16x4 b = *(const bf16x4*)(h2 + (size_t)r1 * Cn + c);
  float4 v;
  v.x = (float)a[0] + (float)b[0];
  v.y = (float)a[1] + (float)b[1];
  v.z = (float)a[2] + (float)b[2];
  v.w = (float)a[3] + (float)b[3];
  *(float4*)(out + (size_t)t * Cn + c) = v;
}

// ---------------- host launch ------------------------------------------------
extern "C" void kernel_launch(void* const* d_in, const int* in_sizes, int n_in,
                              void* d_out, int out_size, void* d_ws, size_t ws_size,
                              hipStream_t stream)
{
  const float* x     = (const float*)d_in[0];
  const float* wgate = (const float*)d_in[1];
  const float* wg    = (const float*)d_in[2];
  const float* wu    = (const float*)d_in[3];
  const float* wd    = (const float*)d_in[4];

  char* ws = (char*)d_ws;
  int* counts = (int*)ws;
  int* fill   = counts + 8;
  int* off    = fill + 8;
  size_t o = 256;
  int*   topk_i   = (int*)(ws + o);   o += (size_t)Tn * 2 * 4;
  float* topk_w   = (float*)(ws + o); o += (size_t)Tn * 2 * 4;
  int*   tok_list = (int*)(ws + o);   o += (size_t)MAXROWS * 4;
  float* wgt_list = (float*)(ws + o); o += (size_t)MAXROWS * 4;
  int*   inv_rows = (int*)(ws + o);   o += (size_t)Tn * 2 * 4;
  o = (o + 255) & ~(size_t)255;
  const size_t WSZ = (size_t)En * Fn * Cn;
  bf16* wgT = (bf16*)(ws + o); o += WSZ * 2;
  bf16* wuT = (bf16*)(ws + o); o += WSZ * 2;
  bf16* wdT = (bf16*)(ws + o); o += WSZ * 2;
  bf16* xg  = (bf16*)(ws + o); o += (size_t)MAXROWS * Cn * 2;
  bf16* h2  = (bf16*)(ws + o); o += (size_t)MAXROWS * Cn * 2;
  bf16* h   = (bf16*)(ws + o);

  size_t havail = ws_size > o ? ws_size - o : 0;
  long crows = (long)(havail / ((size_t)Fn * 2));
  crows &= ~(long)255;
  if (crows > MAXROWS) crows = MAXROWS;
  if (crows < 256) crows = 256;
  const int chunk_rows = (int)crows;
  const int nch = (MAXROWS + chunk_rows - 1) / chunk_rows;

  hipMemsetAsync(counts, 0, 256, stream);
  hipMemsetAsync(tok_list, 0xFF, (size_t)MAXROWS * 4, stream);

  transpose_cvt<<<dim3(Cn / 64, Fn / 64, En), 256, 0, stream>>>(wg, wgT, Cn, Fn);
  transpose_cvt<<<dim3(Cn / 64, Fn / 64, En), 256, 0, stream>>>(wu, wuT, Cn, Fn);
  transpose_cvt<<<dim3(Fn / 64, Cn / 64, En), 256, 0, stream>>>(wd, wdT, Fn, Cn);

  gate_kernel<<<Tn / 4, 256, 0, stream>>>(x, wgate, topk_i, topk_w, counts);
  offsets_kernel<<<1, 64, 0, stream>>>(counts, fill, off);
  scatter_kernel<<<Tn / 256, 256, 0, stream>>>(topk_i, topk_w, fill, tok_list, wgt_list, inv_rows);
  gather_x<<<MAXROWS, 256, 0, stream>>>(x, tok_list, xg);

  for (int c = 0; c < nch; ++c) {
    int row_lo = c * chunk_rows;
    gemm1_kernel<<<dim3(Fn / 64, chunk_rows / 256), 256, 0, stream>>>(
        xg, wgT, wuT, off, counts, wgt_list, h, row_lo);
    gemm2_kernel<<<dim3(Cn / 256, chunk_rows / 128), 256, 0, stream>>>(
        h, wdT, off, h2, row_lo);
  }
  combine_kernel<<<Tn, 256, 0, stream>>>(h2, inv_rows, (float*)d_out);
}